// Round 1
// baseline (719.589 us; speedup 1.0000x reference)
//
#include <hip/hip_runtime.h>

// Voxelization without sorting:
// positions in [0,1), VOXEL=0.01 -> coords in [0,100)^3 -> only 1e6 possible
// voxels. Ordering by the reference hash (cx*1024+cy)*1024+cz equals ordering
// by dense index d=(cx*100+cy)*100+cz (both lexicographic in (cx,cy,cz)), so
// voxel ids (= rank of hash among distinct hashes) come from an occupancy
// prefix-sum over the dense 1e6-cell grid instead of an argsort.

#define GRIDC 100
#define DCELLS (GRIDC * GRIDC * GRIDC)   // 1,000,000
#define SCAN_T 256
#define SCAN_I 4
#define SCAN_CHUNK (SCAN_T * SCAN_I)     // 1024 cells per scan block

__device__ __forceinline__ int cell_of(float px, float py, float pz) {
    // Must match numpy: floor(p / float32(0.01)). hipcc default f32 divide is
    // correctly rounded (IEEE), so this is bit-identical to the reference.
    int cx = (int)floorf(px / 0.01f);
    int cy = (int)floorf(py / 0.01f);
    int cz = (int)floorf(pz / 0.01f);
    // safety clamp only (positions are in [0,1), so this never fires)
    cx = min(max(cx, 0), GRIDC - 1);
    cy = min(max(cy, 0), GRIDC - 1);
    cz = min(max(cz, 0), GRIDC - 1);
    return (cx * GRIDC + cy) * GRIDC + cz;
}

__global__ void init_k(unsigned int* __restrict__ count, float* __restrict__ fsum,
                       unsigned int* __restrict__ minidx,
                       unsigned long long* __restrict__ maxkey) {
    int j = blockIdx.x * blockDim.x + threadIdx.x;
    if (j < DCELLS) {
        count[j] = 0u;
        minidx[j] = 0xFFFFFFFFu;
        fsum[3 * j + 0] = 0.0f;
        fsum[3 * j + 1] = 0.0f;
        fsum[3 * j + 2] = 0.0f;
    }
    if (j == 0) *maxkey = 0ull;
}

__global__ void scatter_k(const float* __restrict__ feat, const float* __restrict__ pos,
                          int N, unsigned int* __restrict__ count,
                          float* __restrict__ fsum, unsigned int* __restrict__ minidx,
                          unsigned long long* __restrict__ maxkey) {
    int i = blockIdx.x * blockDim.x + threadIdx.x;
    if (i >= N) return;
    float px = pos[3 * i + 0], py = pos[3 * i + 1], pz = pos[3 * i + 2];
    int d = cell_of(px, py, pz);
    atomicAdd(&count[d], 1u);
    atomicAdd(&fsum[3 * d + 0], feat[3 * i + 0]);
    atomicAdd(&fsum[3 * d + 1], feat[3 * i + 1]);
    atomicAdd(&fsum[3 * d + 2], feat[3 * i + 2]);
    atomicMin(&minidx[d], (unsigned int)i);            // stable sort: first = min orig idx
    // last sorted point = max (hash, orig idx) lexicographic; N < 2^21 so pack
    unsigned long long key = ((unsigned long long)d << 21) | (unsigned long long)(unsigned int)i;
    atomicMax(maxkey, key);
}

// pass 1: per-block occupied-cell counts
__global__ void blocksum_k(const unsigned int* __restrict__ count,
                           unsigned int* __restrict__ bsums) {
    __shared__ unsigned int s[SCAN_T];
    int base = blockIdx.x * SCAN_CHUNK + threadIdx.x * SCAN_I;
    unsigned int v = 0;
    for (int k = 0; k < SCAN_I; k++) {
        int j = base + k;
        if (j < DCELLS) v += (count[j] > 0u) ? 1u : 0u;
    }
    s[threadIdx.x] = v;
    __syncthreads();
    for (int off = SCAN_T / 2; off > 0; off >>= 1) {
        if (threadIdx.x < off) s[threadIdx.x] += s[threadIdx.x + off];
        __syncthreads();
    }
    if (threadIdx.x == 0) bsums[blockIdx.x] = s[0];
}

// pass 2: single-block exclusive scan of block sums (NB <= 1024)
__global__ void scanbsums_k(unsigned int* __restrict__ bsums, int NB,
                            unsigned int* __restrict__ numvox) {
    __shared__ unsigned int s[1024];
    int t = threadIdx.x;
    unsigned int v = (t < NB) ? bsums[t] : 0u;
    s[t] = v;
    __syncthreads();
    for (int off = 1; off < 1024; off <<= 1) {
        unsigned int add = (t >= off) ? s[t - off] : 0u;
        __syncthreads();
        s[t] += add;
        __syncthreads();
    }
    if (t < NB) bsums[t] = s[t] - v;  // exclusive offset
    if (t == 1023) *numvox = s[1023]; // total occupied voxels
}

// pass 3: per-cell voxel id = block offset + in-block exclusive occupancy scan
__global__ void vid_k(const unsigned int* __restrict__ count,
                      const unsigned int* __restrict__ bsums,
                      unsigned int* __restrict__ vid) {
    __shared__ unsigned int s[SCAN_T];
    int t = threadIdx.x;
    int base = blockIdx.x * SCAN_CHUNK + t * SCAN_I;
    unsigned int occ[SCAN_I];
    unsigned int tsum = 0;
    for (int k = 0; k < SCAN_I; k++) {
        int j = base + k;
        occ[k] = (j < DCELLS && count[j] > 0u) ? 1u : 0u;
        tsum += occ[k];
    }
    s[t] = tsum;
    __syncthreads();
    for (int off = 1; off < SCAN_T; off <<= 1) {
        unsigned int add = (t >= off) ? s[t - off] : 0u;
        __syncthreads();
        s[t] += add;
        __syncthreads();
    }
    unsigned int run = bsums[blockIdx.x] + (s[t] - tsum);
    for (int k = 0; k < SCAN_I; k++) {
        int j = base + k;
        if (j < DCELLS) vid[j] = run;
        run += occ[k];
    }
}

__global__ void cellout_k(const unsigned int* __restrict__ count,
                          const float* __restrict__ fsum,
                          const unsigned int* __restrict__ minidx,
                          const unsigned int* __restrict__ vid,
                          const float* __restrict__ pos,
                          float* __restrict__ out_feat, float* __restrict__ out_pos) {
    int d = blockIdx.x * blockDim.x + threadIdx.x;
    if (d >= DCELLS) return;
    unsigned int c = count[d];
    if (c == 0u) return;
    unsigned int v = vid[d];
    float inv = 1.0f / (float)c;
    out_feat[3 * v + 0] = fsum[3 * d + 0] * inv;
    out_feat[3 * v + 1] = fsum[3 * d + 1] * inv;
    out_feat[3 * v + 2] = fsum[3 * d + 2] * inv;
    unsigned int fi = minidx[d];
    out_pos[3 * v + 0] = pos[3 * fi + 0];
    out_pos[3 * v + 1] = pos[3 * fi + 1];
    out_pos[3 * v + 2] = pos[3 * fi + 2];
}

__global__ void pointout_k(const float* __restrict__ pos,
                           const unsigned int* __restrict__ vid,
                           const unsigned int* __restrict__ numvox,
                           const unsigned long long* __restrict__ maxkey,
                           float* __restrict__ out_feat, float* __restrict__ out_pos,
                           float* __restrict__ out_p2v, int N) {
    int i = blockIdx.x * blockDim.x + threadIdx.x;
    if (i >= N) return;
    float px = pos[3 * i + 0], py = pos[3 * i + 1], pz = pos[3 * i + 2];
    int d = cell_of(px, py, pz);
    out_p2v[i] = (float)vid[d];  // voxel ids < 2^24: exact in f32
    unsigned int nv = *numvox;
    if ((unsigned int)i >= nv) {
        // padded rows: features 0; positions = last sorted point's position
        unsigned int li = (unsigned int)(*maxkey & 0x1FFFFFull);
        out_feat[3 * i + 0] = 0.0f;
        out_feat[3 * i + 1] = 0.0f;
        out_feat[3 * i + 2] = 0.0f;
        out_pos[3 * i + 0] = pos[3 * li + 0];
        out_pos[3 * i + 1] = pos[3 * li + 1];
        out_pos[3 * i + 2] = pos[3 * li + 2];
    }
}

extern "C" void kernel_launch(void* const* d_in, const int* in_sizes, int n_in,
                              void* d_out, int out_size, void* d_ws, size_t ws_size,
                              hipStream_t stream) {
    const float* feat = (const float*)d_in[0];
    const float* pos = (const float*)d_in[1];
    int N = in_sizes[0] / 3;

    // workspace layout (~24 MB):
    char* ws = (char*)d_ws;
    unsigned long long* maxkey = (unsigned long long*)ws;                 // 8 B
    unsigned int* numvox = (unsigned int*)(ws + 8);                       // 4 B (+4 pad)
    unsigned int* count  = (unsigned int*)(ws + 16);                      // 4*D
    unsigned int* minidx = (unsigned int*)(ws + 16 + 4ull * DCELLS);      // 4*D
    unsigned int* vid    = (unsigned int*)(ws + 16 + 8ull * DCELLS);      // 4*D
    unsigned int* bsums  = (unsigned int*)(ws + 16 + 12ull * DCELLS);     // 4 KiB
    float* fsum          = (float*)(ws + 16 + 12ull * DCELLS + 4096);     // 12*D

    float* out_feat = (float*)d_out;
    float* out_pos = out_feat + 3ull * (unsigned long long)N;
    float* out_p2v = out_pos + 3ull * (unsigned long long)N;

    int NB = (DCELLS + SCAN_CHUNK - 1) / SCAN_CHUNK;  // 977 <= 1024

    init_k<<<(DCELLS + 255) / 256, 256, 0, stream>>>(count, fsum, minidx, maxkey);
    scatter_k<<<(N + 255) / 256, 256, 0, stream>>>(feat, pos, N, count, fsum, minidx, maxkey);
    blocksum_k<<<NB, SCAN_T, 0, stream>>>(count, bsums);
    scanbsums_k<<<1, 1024, 0, stream>>>(bsums, NB, numvox);
    vid_k<<<NB, SCAN_T, 0, stream>>>(count, bsums, vid);
    cellout_k<<<(DCELLS + 255) / 256, 256, 0, stream>>>(count, fsum, minidx, vid, pos,
                                                        out_feat, out_pos);
    pointout_k<<<(N + 255) / 256, 256, 0, stream>>>(pos, vid, numvox, maxkey,
                                                    out_feat, out_pos, out_p2v, N);
}